// Round 5
// baseline (637.240 us; speedup 1.0000x reference)
//
#include <hip/hip_runtime.h>
#include <hip/hip_fp16.h>
#include <math.h>

// Problem constants (fixed by reference)
constexpr int I_N = 40000, U_N = 30000, F_N = 30000;
constexpr int NN   = 100000;           // total nodes
constexpr int EE   = 1200000;          // edges (without self loops)
constexpr int ETOT = EE + NN;          // edges + self loops

using f32x2 = __attribute__((ext_vector_type(2))) float;

__device__ __forceinline__ float leaky(float x){ return x > 0.f ? x : 0.2f*x; }

// ---------------- CSR build ----------------
__global__ __launch_bounds__(256) void init_counts_k(int* counts){
  int i = blockIdx.x*256 + threadIdx.x;
  if (i < NN) counts[i] = 1;                   // self loop
}

__global__ __launch_bounds__(256) void count_k(const int* __restrict__ edst, int* counts){
  int e = blockIdx.x*256 + threadIdx.x;
  if (e < EE) atomicAdd(&counts[edst[e]], 1);
}

__global__ __launch_bounds__(256) void scan_blk_k(const int* __restrict__ counts,
                                                  int* __restrict__ row_start,
                                                  int* __restrict__ partials){
  __shared__ int sm[256];
  int t = threadIdx.x, i = blockIdx.x*256 + t;
  int v = (i < NN) ? counts[i] : 0;
  sm[t] = v; __syncthreads();
  for (int off=1; off<256; off<<=1){
    int x = (t >= off) ? sm[t-off] : 0;
    __syncthreads();
    sm[t] += x;
    __syncthreads();
  }
  if (i < NN) row_start[i] = sm[t] - v;        // exclusive
  if (t == 255) partials[blockIdx.x] = sm[255];
}

__global__ __launch_bounds__(512) void scan_part_k(int* partials, int nb){
  __shared__ int sm[512];
  int t = threadIdx.x;
  int v = (t < nb) ? partials[t] : 0;
  sm[t] = v; __syncthreads();
  for (int off=1; off<512; off<<=1){
    int x = (t >= off) ? sm[t-off] : 0;
    __syncthreads();
    sm[t] += x;
    __syncthreads();
  }
  if (t < nb) partials[t] = sm[t] - v;         // exclusive
}

__global__ __launch_bounds__(256) void scan_fix_k(int* row_start, const int* __restrict__ partials,
                                                  int* cursor){
  int i = blockIdx.x*256 + threadIdx.x;
  if (i < NN){
    int v = row_start[i] + partials[blockIdx.x];
    row_start[i] = v;
    cursor[i]    = v;
  }
  if (i == 0) row_start[NN] = ETOT;
}

__global__ __launch_bounds__(256) void scatter_k(const int* __restrict__ esrc,
                                                 const int* __restrict__ edst,
                                                 int* cursor, int* __restrict__ colsrc){
  int e = blockIdx.x*256 + threadIdx.x;
  if (e < EE){
    int d = edst[e];
    int p = atomicAdd(&cursor[d], 1);
    colsrc[p] = esrc[e];
  } else if (e < ETOT){
    int i = e - EE;                            // self loop
    int p = atomicAdd(&cursor[i], 1);
    colsrc[p] = i;
  }
}

// ---------------- GEMM (+ fused attention dot products) ----------------
// XW(fp16) = X @ W (W row-major K x C), plus fp32 asrc/adst epilogue. K-tiled.
// CONCAT: X is the virtual concat [Xa;Xb;Xc] (embeddings), row-width K.
// Inner loop uses float2 packed fma (targets v_pk_fma_f32).
template<int K, int C, int KTILE, int RPB, bool CONCAT>
__global__ __launch_bounds__(256) void gemm_att_k(
    const float* __restrict__ Xa, const float* __restrict__ Xb, const float* __restrict__ Xc,
    const float* __restrict__ W,
    const float* __restrict__ atts, const float* __restrict__ attd,
    __half* __restrict__ XWH, float* __restrict__ asrc, float* __restrict__ adst)
{
  constexpr int TPR   = C/4;        // threads per row
  constexpr int SLOTS = 256/TPR;    // concurrent rows
  constexpr int RPT   = RPB/SLOTS;  // rows per thread
  constexpr int HTOT  = C/64;
  __shared__ float Ws[KTILE*C];
  __shared__ float Xs[RPB*K];
  int t = threadIdx.x;
  long rbase = (long)blockIdx.x * RPB;

  if constexpr (CONCAT){
    for (int i = t; i < RPB*K/4; i += 256){
      long gi = rbase*(K/4) + i;               // float4 index in concat space
      float4 v;
      if      (gi < (long)I_N*(K/4))          v = ((const float4*)Xa)[gi];
      else if (gi < (long)(I_N+U_N)*(K/4))    v = ((const float4*)Xb)[gi - (long)I_N*(K/4)];
      else                                    v = ((const float4*)Xc)[gi - (long)(I_N+U_N)*(K/4)];
      ((float4*)Xs)[i] = v;
    }
  } else {
    for (int i = t; i < RPB*K/4; i += 256)
      ((float4*)Xs)[i] = ((const float4*)(Xa + rbase*K))[i];
  }

  int slot = t / TPR;
  int c4   = (t % TPR)*4;
  f32x2 accA[RPT], accB[RPT];
  #pragma unroll
  for (int i = 0; i < RPT; ++i){ accA[i] = (f32x2){0.f,0.f}; accB[i] = (f32x2){0.f,0.f}; }

  for (int kt = 0; kt < K; kt += KTILE){
    __syncthreads();
    for (int i = t; i < KTILE*C/4; i += 256)
      ((float4*)Ws)[i] = ((const float4*)(W + (long)kt*C))[i];
    __syncthreads();
    #pragma unroll 2
    for (int k = 0; k < KTILE; k += 4){
      float4 xv[RPT];
      #pragma unroll
      for (int i = 0; i < RPT; ++i)
        xv[i] = *(const float4*)&Xs[(slot + i*SLOTS)*K + kt + k];
      #pragma unroll
      for (int kk = 0; kk < 4; ++kk){
        const float* wrow = &Ws[(k+kk)*C + c4];
        f32x2 w0 = *(const f32x2*)wrow;
        f32x2 w1 = *(const f32x2*)(wrow + 2);
        #pragma unroll
        for (int i = 0; i < RPT; ++i){
          float xvv = (kk==0)?xv[i].x:(kk==1)?xv[i].y:(kk==2)?xv[i].z:xv[i].w;
          f32x2 xb = {xvv, xvv};
          accA[i] = __builtin_elementwise_fma(xb, w0, accA[i]);
          accB[i] = __builtin_elementwise_fma(xb, w1, accB[i]);
        }
      }
    }
  }

  int head = c4 >> 6;
  float4 as4 = *(const float4*)&atts[head*64 + (c4&63)];
  float4 ad4 = *(const float4*)&attd[head*64 + (c4&63)];
  #pragma unroll
  for (int i = 0; i < RPT; ++i){
    float4 acc = make_float4(accA[i].x, accA[i].y, accB[i].x, accB[i].y);
    float ps = acc.x*as4.x + acc.y*as4.y + acc.z*as4.z + acc.w*as4.w;
    float pd = acc.x*ad4.x + acc.y*ad4.y + acc.z*ad4.z + acc.w*ad4.w;
    #pragma unroll
    for (int m = 1; m < 16; m <<= 1){
      ps += __shfl_xor(ps, m, 64);
      pd += __shfl_xor(pd, m, 64);
    }
    long r = rbase + slot + i*SLOTS;
    if ((t & 15) == 0){
      asrc[r*HTOT + head] = ps; adst[r*HTOT + head] = pd;
    }
    union { __half2 h2[2]; uint2 u2; } pk;
    pk.h2[0] = __floats2half2_rn(acc.x, acc.y);
    pk.h2[1] = __floats2half2_rn(acc.z, acc.w);
    *(uint2*)&XWH[r*C + c4] = pk.u2;
  }
}

// ---------------- aggregation: online softmax + weighted sum (+ fused fin/final) ------
// 1 wave per dst node, XW rows in fp16.
// H==2 (row 256B): 4 edges per wave-load; slot = lane>>4, colgroup cg = lane&15 (8 cols).
// H==1 (row 128B): 8 edges per wave-load; slot = lane>>3, cg = lane&7.
// LAYER: 1 = fin=x0(emb)+0.5*e1, hbuf=relu ; 2 = fin+=0.5*e2, hbuf=relu
//        3 = out=(fin+x3)/4 to both output slots
// Writes pm per node: H2 -> (mx0,idv0,mx1,idv1); H1 -> (mx,idv). Alpha computed separately.
template<int H, int LAYER>
__global__ __launch_bounds__(256) void aggregate_k(
    const __half* __restrict__ XWH, const float* __restrict__ asrc, const float* __restrict__ adst,
    const int* __restrict__ row_start, const int* __restrict__ colsrc,
    const float* __restrict__ bias, float* __restrict__ pm,
    float* __restrict__ hbuf, float* __restrict__ fin,
    const float* __restrict__ embi, const float* __restrict__ embu, const float* __restrict__ embf,
    float* __restrict__ outp)
{
  constexpr int C = H*64;
  int wid  = (blockIdx.x*256 + threadIdx.x) >> 6;
  int lane = threadIdx.x & 63;
  if (wid >= NN) return;
  int n0 = row_start[wid], n1 = row_start[wid+1];

  float ad[H];
  if constexpr (H==2){ float2 t = ((const float2*)adst)[wid]; ad[0]=t.x; ad[1]=t.y; }
  else                 ad[0] = adst[wid];

  constexpr int SL_SH = (H==2) ? 4 : 3;       // slot shift
  const int slot = lane >> SL_SH;
  const int cg   = lane & ((1<<SL_SH)-1);     // col-group: 8 cols each
  const int hd   = (H==2) ? (cg>>3) : 0;      // head of this lane's cols

  float mx[H], den[H];
  #pragma unroll
  for (int h=0; h<H; ++h){ mx[h] = -3.402823466e38f; den[h] = 0.f; }
  f32x2 accp[4];
  #pragma unroll
  for (int i=0;i<4;++i) accp[i] = (f32x2){0.f,0.f};

  int s = 0;
  float p[H];
  #pragma unroll
  for (int h=0; h<H; ++h) p[h] = 0.f;

  for (int base = n0; base < n1; base += 64){
    int cnt = n1 - base; if (cnt > 64) cnt = 64;
    float e[H];
    #pragma unroll
    for (int h=0; h<H; ++h) e[h] = -3.402823466e38f;
    if (lane < cnt){
      s = colsrc[base + lane];
      if constexpr (H==2){
        float2 a = ((const float2*)asrc)[s];
        e[0] = leaky(a.x + ad[0]); e[1] = leaky(a.y + ad[1]);
      } else {
        e[0] = leaky(asrc[s] + ad[0]);
      }
    }
    float sc[H];
    #pragma unroll
    for (int h=0; h<H; ++h){
      float bm = e[h];
      #pragma unroll
      for (int m=1; m<64; m<<=1) bm = fmaxf(bm, __shfl_xor(bm, m, 64));
      float nm = fmaxf(mx[h], bm);
      p[h] = (lane < cnt) ? __expf(e[h] - nm) : 0.f;
      if (base == n0){
        den[h] = p[h]; sc[h] = 1.f;
      } else {
        sc[h] = __expf(mx[h] - nm);
        den[h] = den[h]*sc[h] + p[h];
      }
      mx[h] = nm;
    }
    if (base != n0){
      float asc = (H==2) ? sc[hd] : sc[0];
      f32x2 av = {asc, asc};
      #pragma unroll
      for (int i=0;i<4;++i) accp[i] *= av;
    }

    constexpr int EPI = 64 >> SL_SH;           // edge slots per load
    for (int j = 0; j < cnt; j += 2*EPI){
      float4 raw[2]; float q[2];
      #pragma unroll
      for (int u=0; u<2; ++u){
        int ei  = j + u*EPI + slot;
        int eic = ei < cnt ? ei : 0;
        int su  = __shfl(s, eic, 64);
        if constexpr (H==2){
          float q0 = __shfl(p[0], eic, 64);
          float q1 = __shfl(p[1], eic, 64);
          q[u] = (ei < cnt) ? (hd ? q1 : q0) : 0.f;
        } else {
          float q0 = __shfl(p[0], eic, 64);
          q[u] = (ei < cnt) ? q0 : 0.f;
        }
        raw[u] = *(const float4*)&XWH[(long)su*C + cg*8];
      }
      #pragma unroll
      for (int u=0; u<2; ++u){
        union { float4 f4; __half2 h2[4]; } cv; cv.f4 = raw[u];
        f32x2 qq = {q[u], q[u]};
        #pragma unroll
        for (int i=0;i<4;++i){
          float2 f = __half22float2(cv.h2[i]);
          f32x2 ff = {f.x, f.y};
          accp[i] = __builtin_elementwise_fma(qq, ff, accp[i]);
        }
      }
    }
  }

  float idv[H];
  #pragma unroll
  for (int h=0; h<H; ++h){
    #pragma unroll
    for (int m=1; m<64; m<<=1) den[h] += __shfl_xor(den[h], m, 64);
    idv[h] = 1.0f/(den[h] + 1e-16f);
  }

  float accv[8];
  #pragma unroll
  for (int i=0;i<4;++i){ accv[2*i] = accp[i].x; accv[2*i+1] = accp[i].y; }

  // combine edge-slot partial sums: lanes with same cg
  #pragma unroll
  for (int i=0;i<8;++i){
    if constexpr (H==1) accv[i] += __shfl_xor(accv[i], 8, 64);
    accv[i] += __shfl_xor(accv[i], 16, 64);
    accv[i] += __shfl_xor(accv[i], 32, 64);
  }

  float myId = (H==2) ? idv[hd] : idv[0];
  float4 b0 = *(const float4*)&bias[cg*8];
  float4 b1 = *(const float4*)&bias[cg*8 + 4];
  float o[8];
  o[0]=accv[0]*myId+b0.x; o[1]=accv[1]*myId+b0.y; o[2]=accv[2]*myId+b0.z; o[3]=accv[3]*myId+b0.w;
  o[4]=accv[4]*myId+b1.x; o[5]=accv[5]*myId+b1.y; o[6]=accv[6]*myId+b1.z; o[7]=accv[7]*myId+b1.w;

  if constexpr (LAYER==1 || LAYER==2){
    if (lane < 16){
      float4 r0 = make_float4(fmaxf(o[0],0.f), fmaxf(o[1],0.f), fmaxf(o[2],0.f), fmaxf(o[3],0.f));
      float4 r1 = make_float4(fmaxf(o[4],0.f), fmaxf(o[5],0.f), fmaxf(o[6],0.f), fmaxf(o[7],0.f));
      *(float4*)&hbuf[(long)wid*C + cg*8]     = r0;
      *(float4*)&hbuf[(long)wid*C + cg*8 + 4] = r1;
    }
    // head0 + head1 per feature d: lane l (cg<8) pairs with l+8
    float f[8];
    #pragma unroll
    for (int i=0;i<8;++i) f[i] = o[i] + __shfl_xor(o[i], 8, 64);
    if (lane < 8){
      float4 f0 = make_float4(f[0],f[1],f[2],f[3]);
      float4 f1 = make_float4(f[4],f[5],f[6],f[7]);
      float4* fp = (float4*)&fin[(long)wid*64 + lane*8];
      if constexpr (LAYER==1){
        const float4* src; long off;
        if      (wid < I_N)      { src=(const float4*)embi; off=(long)wid*16; }
        else if (wid < I_N+U_N)  { src=(const float4*)embu; off=(long)(wid-I_N)*16; }
        else                     { src=(const float4*)embf; off=(long)(wid-I_N-U_N)*16; }
        float4 xa = src[off + lane*2], xb = src[off + lane*2 + 1];
        fp[0] = make_float4(xa.x+f0.x*0.5f, xa.y+f0.y*0.5f, xa.z+f0.z*0.5f, xa.w+f0.w*0.5f);
        fp[1] = make_float4(xb.x+f1.x*0.5f, xb.y+f1.y*0.5f, xb.z+f1.z*0.5f, xb.w+f1.w*0.5f);
      } else {
        float4 ca = fp[0], cb = fp[1];
        fp[0] = make_float4(ca.x+f0.x*0.5f, ca.y+f0.y*0.5f, ca.z+f0.z*0.5f, ca.w+f0.w*0.5f);
        fp[1] = make_float4(cb.x+f1.x*0.5f, cb.y+f1.y*0.5f, cb.z+f1.z*0.5f, cb.w+f1.w*0.5f);
      }
    }
  } else {
    // LAYER 3: final = (fin + x3)/4 -> both output copies
    if (lane < 8){
      const float4* fp = (const float4*)&fin[(long)wid*64 + lane*8];
      float4 ca = fp[0], cb = fp[1];
      float4 t0 = make_float4((ca.x+o[0])*0.25f,(ca.y+o[1])*0.25f,(ca.z+o[2])*0.25f,(ca.w+o[3])*0.25f);
      float4 t1 = make_float4((cb.x+o[4])*0.25f,(cb.y+o[5])*0.25f,(cb.z+o[6])*0.25f,(cb.w+o[7])*0.25f);
      ((float4*)outp)[(long)wid*16 + lane*2]            = t0;
      ((float4*)outp)[(long)wid*16 + lane*2 + 1]        = t1;
      ((float4*)outp)[(long)(NN+wid)*16 + lane*2]       = t0;
      ((float4*)outp)[(long)(NN+wid)*16 + lane*2 + 1]   = t1;
    }
  }

  if (lane == 0){
    if constexpr (H==2) ((float4*)pm)[wid] = make_float4(mx[0], idv[0], mx[1], idv[1]);
    else                ((float2*)pm)[wid] = make_float2(mx[0], idv[0]);
  }
}

// ---------------- alpha output (edge-parallel, coalesced writes) ----------------
template<int H>
__global__ __launch_bounds__(256) void alpha_kk(
    const int* __restrict__ esrc, const int* __restrict__ edst,
    const float* __restrict__ asrc, const float* __restrict__ adst,
    const float* __restrict__ pm, float* __restrict__ out)
{
  int e = blockIdx.x*256 + threadIdx.x;
  if (e >= ETOT) return;
  int s, d;
  if (e < EE){ s = esrc[e]; d = edst[e]; } else { s = d = e - EE; }
  if constexpr (H==2){
    float2 a  = ((const float2*)asrc)[s];
    float2 b  = ((const float2*)adst)[d];
    float4 mi = ((const float4*)pm)[d];
    float2 o;
    o.x = __expf(leaky(a.x + b.x) - mi.x) * mi.y;
    o.y = __expf(leaky(a.y + b.y) - mi.z) * mi.w;
    ((float2*)out)[e] = o;
  } else {
    float2 mi = ((const float2*)pm)[d];
    out[e] = __expf(leaky(asrc[s] + adst[d]) - mi.x) * mi.y;
  }
}

extern "C" void kernel_launch(void* const* d_in, const int* in_sizes, int n_in,
                              void* d_out, int out_size, void* d_ws, size_t ws_size,
                              hipStream_t stream)
{
  (void)in_sizes; (void)n_in; (void)out_size; (void)ws_size;
  const int*   eidx  = (const int*)d_in[0];
  const int*   esrc  = eidx;
  const int*   edst  = eidx + EE;
  const float* emb_i = (const float*)d_in[1];
  const float* emb_u = (const float*)d_in[2];
  const float* emb_f = (const float*)d_in[3];
  const float* W1    = (const float*)d_in[4];
  const float* as1   = (const float*)d_in[5];
  const float* ad1   = (const float*)d_in[6];
  const float* b1    = (const float*)d_in[7];
  const float* W2    = (const float*)d_in[8];
  const float* as2   = (const float*)d_in[9];
  const float* ad2   = (const float*)d_in[10];
  const float* b2    = (const float*)d_in[11];
  const float* W3    = (const float*)d_in[12];
  const float* as3   = (const float*)d_in[13];
  const float* ad3   = (const float*)d_in[14];
  const float* b3    = (const float*)d_in[15];
  float* out = (float*)d_out;

  // workspace layout (256B aligned)
  char* p = (char*)d_ws;
  auto alloc = [&](size_t bytes)->char* {
    char* r = p; p += (bytes + 255) & ~(size_t)255; return r;
  };
  float*  fin  = (float*)alloc((size_t)NN*64*4);
  float*  hbuf = (float*)alloc((size_t)NN*128*4);
  __half* xwh  = (__half*)alloc((size_t)NN*128*2);
  float*  asrc = (float*)alloc((size_t)NN*2*4);
  float*  adst = (float*)alloc((size_t)NN*2*4);
  float*  pm   = (float*)alloc((size_t)NN*4*4);
  int* counts    = (int*)alloc((size_t)NN*4);
  int* row_start = (int*)alloc((size_t)(NN+1)*4);
  int* cursor    = (int*)alloc((size_t)NN*4);
  int* colsrc    = (int*)alloc((size_t)ETOT*4);
  int* partials  = (int*)alloc(512*4);

  constexpr int NB_N  = (NN  +255)/256;   // 391
  constexpr int NB_E  = (EE  +255)/256;   // 4688
  constexpr int NB_ET = (ETOT+255)/256;   // 5079

  float* alpha1 = out + (size_t)12800000;
  float* alpha2 = out + (size_t)15400000;
  float* alpha3 = out + (size_t)18000000;

  // CSR build (shared by all layers)
  init_counts_k<<<NB_N ,256,0,stream>>>(counts);
  count_k      <<<NB_E ,256,0,stream>>>(edst, counts);
  scan_blk_k   <<<NB_N ,256,0,stream>>>(counts, row_start, partials);
  scan_part_k  <<<1    ,512,0,stream>>>(partials, NB_N);
  scan_fix_k   <<<NB_N ,256,0,stream>>>(row_start, partials, cursor);
  scatter_k    <<<NB_ET,256,0,stream>>>(esrc, edst, cursor, colsrc);

  // ---- Layer 1: K=64 -> C=128 (H=2), X = concat(embeddings) ----
  gemm_att_k<64,128,64,32,true><<<NN/32,256,0,stream>>>(emb_i, emb_u, emb_f, W1, as1, ad1, xwh, asrc, adst);
  aggregate_k<2,1><<<NN/4,256,0,stream>>>(xwh, asrc, adst, row_start, colsrc, b1, pm,
                                          hbuf, fin, emb_i, emb_u, emb_f, nullptr);
  alpha_kk<2><<<NB_ET,256,0,stream>>>(esrc, edst, asrc, adst, pm, alpha1);

  // ---- Layer 2: K=128 -> C=128 (H=2) ----
  gemm_att_k<128,128,64,32,false><<<NN/32,256,0,stream>>>(hbuf, nullptr, nullptr, W2, as2, ad2, xwh, asrc, adst);
  aggregate_k<2,2><<<NN/4,256,0,stream>>>(xwh, asrc, adst, row_start, colsrc, b2, pm,
                                          hbuf, fin, nullptr, nullptr, nullptr, nullptr);
  alpha_kk<2><<<NB_ET,256,0,stream>>>(esrc, edst, asrc, adst, pm, alpha2);

  // ---- Layer 3: K=128 -> C=64 (H=1), fused final write ----
  gemm_att_k<128,64,128,32,false><<<NN/32,256,0,stream>>>(hbuf, nullptr, nullptr, W3, as3, ad3, xwh, asrc, adst);
  aggregate_k<1,3><<<NN/4,256,0,stream>>>(xwh, asrc, adst, row_start, colsrc, b3, pm,
                                          nullptr, fin, nullptr, nullptr, nullptr, out);
  alpha_kk<1><<<NB_ET,256,0,stream>>>(esrc, edst, asrc, adst, pm, alpha3);
}

// Round 6
// 527.507 us; speedup vs baseline: 1.2080x; 1.2080x over previous
//
#include <hip/hip_runtime.h>
#include <hip/hip_fp16.h>
#include <math.h>

// Problem constants (fixed by reference)
constexpr int I_N = 40000, U_N = 30000, F_N = 30000;
constexpr int NN   = 100000;           // total nodes
constexpr int EE   = 1200000;          // edges (without self loops)
constexpr int ETOT = EE + NN;          // edges + self loops
constexpr int NBUCK = (NN + 511)/512;  // 196 dst-buckets of 512 nodes

__device__ __forceinline__ float leaky(float x){ return x > 0.f ? x : 0.2f*x; }

// ---------------- binned CSR build (no random global atomics in hot path) ----------------
__global__ __launch_bounds__(256) void zerob_k(int* bsize){
  int i = threadIdx.x;
  if (i < NBUCK) bsize[i] = 0;
}

// A0: bucket histogram (per-block LDS hist, ~100k global atomics total)
__global__ __launch_bounds__(256) void hist_k(const int* __restrict__ edst, int* __restrict__ bsize){
  __shared__ int h[NBUCK];
  for (int i = threadIdx.x; i < NBUCK; i += 256) h[i] = 0;
  __syncthreads();
  int stride = gridDim.x*256;
  for (int e = blockIdx.x*256 + threadIdx.x; e < EE; e += stride)
    atomicAdd(&h[edst[e] >> 9], 1);
  __syncthreads();
  for (int i = threadIdx.x; i < NBUCK; i += 256)
    if (h[i]) atomicAdd(&bsize[i], h[i]);
}

// scan: bucket bases for binned array (ebase) and CSR (rbase, incl self loops)
__global__ __launch_bounds__(256) void bscan_k(const int* __restrict__ bsize,
                                               int* __restrict__ ebase, int* __restrict__ rbase,
                                               int* __restrict__ gcur, int* __restrict__ row_start){
  __shared__ int sb[NBUCK], se[NBUCK], sr[NBUCK];
  int t = threadIdx.x;
  for (int i = t; i < NBUCK; i += 256) sb[i] = bsize[i];
  __syncthreads();
  if (t == 0){
    int e = 0, r = 0;
    for (int b = 0; b < NBUCK; ++b){
      int nloc = NN - b*512; if (nloc > 512) nloc = 512;
      se[b] = e; sr[b] = r;
      e += sb[b]; r += sb[b] + nloc;
    }
    row_start[NN] = ETOT;
  }
  __syncthreads();
  for (int i = t; i < NBUCK; i += 256){
    ebase[i] = se[i]; gcur[i] = se[i]; rbase[i] = sr[i];
  }
}

// A1: place edges into bucket-contiguous binned[] as (eid<<32)|(dstlow<<17)|src
__global__ __launch_bounds__(256) void binplace_k(const int* __restrict__ esrc,
                                                  const int* __restrict__ edst,
                                                  int* __restrict__ gcur,
                                                  unsigned long long* __restrict__ binned){
  constexpr int CHUNK = 4096;
  __shared__ int ls[CHUNK], ld[CHUNK];
  __shared__ int h[NBUCK], bb[NBUCK], cur[NBUCK];
  long e0 = (long)blockIdx.x * CHUNK;
  int n = (int)(EE - e0); if (n > CHUNK) n = CHUNK;
  for (int i = threadIdx.x; i < NBUCK; i += 256){ h[i] = 0; cur[i] = 0; }
  __syncthreads();
  for (int i = threadIdx.x; i < n; i += 256){
    int s = esrc[e0+i], d = edst[e0+i];
    ls[i] = s; ld[i] = d;
    atomicAdd(&h[d >> 9], 1);
  }
  __syncthreads();
  for (int b = threadIdx.x; b < NBUCK; b += 256)
    bb[b] = h[b] ? atomicAdd(&gcur[b], h[b]) : 0;
  __syncthreads();
  for (int i = threadIdx.x; i < n; i += 256){
    int d = ld[i], b = d >> 9;
    int p = bb[b] + atomicAdd(&cur[b], 1);
    unsigned long long v = ((unsigned long long)(unsigned)(e0+i) << 32)
                         | (unsigned)(ls[i] | ((d & 511) << 17));
    binned[p] = v;
  }
}

// B: per bucket -- LDS counts, scan, CSR segment build (colsrc + eids + row_start)
__global__ __launch_bounds__(512) void bbuild_k(const unsigned long long* __restrict__ binned,
                                                const int* __restrict__ bsize,
                                                const int* __restrict__ ebase, const int* __restrict__ rbase,
                                                int* __restrict__ row_start,
                                                int* __restrict__ colsrc, int* __restrict__ eids){
  __shared__ int sm[512], curs[512];
  int b = blockIdx.x, t = threadIdx.x;
  int nbase = b*512;
  int NLOC = NN - nbase; if (NLOC > 512) NLOC = 512;
  int sz = bsize[b], eb = ebase[b], rb = rbase[b];
  sm[t] = (t < NLOC) ? 1 : 0;                  // self loop
  __syncthreads();
  for (int i = t; i < sz; i += 512){
    int lo = (int)(binned[eb+i] & 0xFFFFFFFFu);
    atomicAdd(&sm[(lo >> 17) & 511], 1);
  }
  __syncthreads();
  int myc = sm[t];
  for (int off = 1; off < 512; off <<= 1){
    int x = (t >= off) ? sm[t-off] : 0;
    __syncthreads();
    sm[t] += x;
    __syncthreads();
  }
  int excl = sm[t] - myc;
  if (t < NLOC){
    row_start[nbase+t] = rb + excl;
    colsrc[rb+excl] = nbase + t;               // self loop first in segment
    eids[rb+excl]   = EE + nbase + t;
  }
  curs[t] = excl + ((t < NLOC) ? 1 : 0);
  __syncthreads();
  for (int i = t; i < sz; i += 512){
    unsigned long long v = binned[eb+i];
    int lo  = (int)(v & 0xFFFFFFFFu);
    int dl  = (lo >> 17) & 511;
    int src = lo & 0x1FFFF;
    int p = rb + atomicAdd(&curs[dl], 1);
    colsrc[p] = src;
    eids[p]   = (int)(v >> 32);
  }
}

// ---------------- GEMM (+ fused attention dot products) ----------------
// XW(fp16) = X @ W (W row-major K x C), plus fp32 asrc/adst epilogue. K-tiled.
// CONCAT: X is the virtual concat [Xa;Xb;Xc] (embeddings), row-width K.
template<int K, int C, int KTILE, int RPB, bool CONCAT>
__global__ __launch_bounds__(256) void gemm_att_k(
    const float* __restrict__ Xa, const float* __restrict__ Xb, const float* __restrict__ Xc,
    const float* __restrict__ W,
    const float* __restrict__ atts, const float* __restrict__ attd,
    __half* __restrict__ XWH, float* __restrict__ asrc, float* __restrict__ adst)
{
  constexpr int TPR   = C/4;        // threads per row
  constexpr int SLOTS = 256/TPR;    // concurrent rows
  constexpr int RPT   = RPB/SLOTS;  // rows per thread
  constexpr int HTOT  = C/64;
  __shared__ float Ws[KTILE*C];
  __shared__ float Xs[RPB*K];
  int t = threadIdx.x;
  long rbase = (long)blockIdx.x * RPB;

  if constexpr (CONCAT){
    for (int i = t; i < RPB*K/4; i += 256){
      long gi = rbase*(K/4) + i;               // float4 index in concat space
      float4 v;
      if      (gi < (long)I_N*(K/4))          v = ((const float4*)Xa)[gi];
      else if (gi < (long)(I_N+U_N)*(K/4))    v = ((const float4*)Xb)[gi - (long)I_N*(K/4)];
      else                                    v = ((const float4*)Xc)[gi - (long)(I_N+U_N)*(K/4)];
      ((float4*)Xs)[i] = v;
    }
  } else {
    for (int i = t; i < RPB*K/4; i += 256)
      ((float4*)Xs)[i] = ((const float4*)(Xa + rbase*K))[i];
  }

  int slot = t / TPR;
  int c4   = (t % TPR)*4;
  float4 acc[RPT];
  #pragma unroll
  for (int i = 0; i < RPT; ++i) acc[i] = make_float4(0,0,0,0);

  for (int kt = 0; kt < K; kt += KTILE){
    __syncthreads();
    for (int i = t; i < KTILE*C/4; i += 256)
      ((float4*)Ws)[i] = ((const float4*)(W + (long)kt*C))[i];
    __syncthreads();
    #pragma unroll 2
    for (int k = 0; k < KTILE; k += 4){
      float4 xv[RPT];
      #pragma unroll
      for (int i = 0; i < RPT; ++i)
        xv[i] = *(const float4*)&Xs[(slot + i*SLOTS)*K + kt + k];
      #pragma unroll
      for (int kk = 0; kk < 4; ++kk){
        float4 w = *(const float4*)&Ws[(k+kk)*C + c4];
        #pragma unroll
        for (int i = 0; i < RPT; ++i){
          float xvv = (kk==0)?xv[i].x:(kk==1)?xv[i].y:(kk==2)?xv[i].z:xv[i].w;
          acc[i].x = fmaf(xvv,w.x,acc[i].x); acc[i].y = fmaf(xvv,w.y,acc[i].y);
          acc[i].z = fmaf(xvv,w.z,acc[i].z); acc[i].w = fmaf(xvv,w.w,acc[i].w);
        }
      }
    }
  }

  int head = c4 >> 6;
  float4 as4 = *(const float4*)&atts[head*64 + (c4&63)];
  float4 ad4 = *(const float4*)&attd[head*64 + (c4&63)];
  #pragma unroll
  for (int i = 0; i < RPT; ++i){
    float ps = acc[i].x*as4.x + acc[i].y*as4.y + acc[i].z*as4.z + acc[i].w*as4.w;
    float pd = acc[i].x*ad4.x + acc[i].y*ad4.y + acc[i].z*ad4.z + acc[i].w*ad4.w;
    #pragma unroll
    for (int m = 1; m < 16; m <<= 1){
      ps += __shfl_xor(ps, m, 64);
      pd += __shfl_xor(pd, m, 64);
    }
    long r = rbase + slot + i*SLOTS;
    if ((t & 15) == 0){
      asrc[r*HTOT + head] = ps; adst[r*HTOT + head] = pd;
    }
    union { __half2 h2[2]; uint2 u2; } pk;
    pk.h2[0] = __floats2half2_rn(acc[i].x, acc[i].y);
    pk.h2[1] = __floats2half2_rn(acc[i].z, acc[i].w);
    *(uint2*)&XWH[r*C + c4] = pk.u2;
  }
}

// ---------------- aggregation: online softmax + weighted sum + fused alpha/final ------
// 1 wave per dst node, XW rows in fp16.
// H==2 (row 256B): 4 edges per wave-load; slot = lane>>4, colgroup cg = lane&15 (8 cols).
// H==1 (row 128B): 8 edges per wave-load; slot = lane>>3, cg = lane&7.
// LAYER: 1 = fin=x0(emb)+0.5*e1, hbuf=relu ; 2 = fin+=0.5*e2, hbuf=relu
//        3 = out=(fin+x3)/4 to both output slots
template<int H, int LAYER>
__global__ __launch_bounds__(256) void aggregate_k(
    const __half* __restrict__ XWH, const float* __restrict__ asrc, const float* __restrict__ adst,
    const int* __restrict__ row_start, const int* __restrict__ colsrc, const int* __restrict__ eids,
    const float* __restrict__ bias, float* __restrict__ aout,
    float* __restrict__ hbuf, float* __restrict__ fin,
    const float* __restrict__ embi, const float* __restrict__ embu, const float* __restrict__ embf,
    float* __restrict__ outp)
{
  constexpr int C = H*64;
  int wid  = (blockIdx.x*256 + threadIdx.x) >> 6;
  int lane = threadIdx.x & 63;
  if (wid >= NN) return;
  int n0 = row_start[wid], n1 = row_start[wid+1];
  int segLen = n1 - n0;

  float ad[H];
  if constexpr (H==2){ float2 t = ((const float2*)adst)[wid]; ad[0]=t.x; ad[1]=t.y; }
  else                 ad[0] = adst[wid];

  constexpr int SL_SH = (H==2) ? 4 : 3;       // slot shift
  const int slot = lane >> SL_SH;
  const int cg   = lane & ((1<<SL_SH)-1);     // col-group: 8 cols each
  const int hd   = (H==2) ? (cg>>3) : 0;      // head of this lane's cols

  float mx[H], den[H];
  #pragma unroll
  for (int h=0; h<H; ++h){ mx[h] = -3.402823466e38f; den[h] = 0.f; }
  float accv[8];
  #pragma unroll
  for (int i=0;i<8;++i) accv[i] = 0.f;

  int s = 0, eid = 0;
  float p[H];
  #pragma unroll
  for (int h=0; h<H; ++h) p[h] = 0.f;

  for (int base = n0; base < n1; base += 64){
    int cnt = n1 - base; if (cnt > 64) cnt = 64;
    float e[H];
    #pragma unroll
    for (int h=0; h<H; ++h) e[h] = -3.402823466e38f;
    if (lane < cnt){
      s   = colsrc[base + lane];
      eid = eids[base + lane];
      if constexpr (H==2){
        float2 a = ((const float2*)asrc)[s];
        e[0] = leaky(a.x + ad[0]); e[1] = leaky(a.y + ad[1]);
      } else {
        e[0] = leaky(asrc[s] + ad[0]);
      }
    }
    float sc[H];
    #pragma unroll
    for (int h=0; h<H; ++h){
      float bm = e[h];
      #pragma unroll
      for (int m=1; m<64; m<<=1) bm = fmaxf(bm, __shfl_xor(bm, m, 64));
      float nm = fmaxf(mx[h], bm);
      p[h] = (lane < cnt) ? __expf(e[h] - nm) : 0.f;
      if (base == n0){
        den[h] = p[h]; sc[h] = 1.f;
      } else {
        sc[h] = __expf(mx[h] - nm);
        den[h] = den[h]*sc[h] + p[h];
      }
      mx[h] = nm;
    }
    if (base != n0){
      float asc = (H==2) ? sc[hd] : sc[0];
      #pragma unroll
      for (int i=0;i<8;++i) accv[i] *= asc;
    }

    constexpr int EPI = 64 >> SL_SH;           // edge slots per load
    for (int j = 0; j < cnt; j += 2*EPI){
      float4 raw[2]; float q[2];
      #pragma unroll
      for (int u=0; u<2; ++u){
        int ei  = j + u*EPI + slot;
        int eic = ei < cnt ? ei : 0;
        int su  = __shfl(s, eic, 64);
        if constexpr (H==2){
          float q0 = __shfl(p[0], eic, 64);
          float q1 = __shfl(p[1], eic, 64);
          q[u] = (ei < cnt) ? (hd ? q1 : q0) : 0.f;
        } else {
          float q0 = __shfl(p[0], eic, 64);
          q[u] = (ei < cnt) ? q0 : 0.f;
        }
        raw[u] = *(const float4*)&XWH[(long)su*C + cg*8];
      }
      #pragma unroll
      for (int u=0; u<2; ++u){
        union { float4 f4; __half2 h2[4]; } cv; cv.f4 = raw[u];
        #pragma unroll
        for (int i=0;i<4;++i){
          float2 f = __half22float2(cv.h2[i]);
          accv[2*i]   = fmaf(q[u], f.x, accv[2*i]);
          accv[2*i+1] = fmaf(q[u], f.y, accv[2*i+1]);
        }
      }
    }
  }

  float idv[H];
  #pragma unroll
  for (int h=0; h<H; ++h){
    #pragma unroll
    for (int m=1; m<64; m<<=1) den[h] += __shfl_xor(den[h], m, 64);
    idv[h] = 1.0f/(den[h] + 1e-16f);
  }

  // combine edge-slot partial sums: lanes with same cg
  #pragma unroll
  for (int i=0;i<8;++i){
    if constexpr (H==1) accv[i] += __shfl_xor(accv[i], 8, 64);
    accv[i] += __shfl_xor(accv[i], 16, 64);
    accv[i] += __shfl_xor(accv[i], 32, 64);
  }

  float myId = (H==2) ? idv[hd] : idv[0];
  float4 b0 = *(const float4*)&bias[cg*8];
  float4 b1 = *(const float4*)&bias[cg*8 + 4];
  float o[8];
  o[0]=accv[0]*myId+b0.x; o[1]=accv[1]*myId+b0.y; o[2]=accv[2]*myId+b0.z; o[3]=accv[3]*myId+b0.w;
  o[4]=accv[4]*myId+b1.x; o[5]=accv[5]*myId+b1.y; o[6]=accv[6]*myId+b1.z; o[7]=accv[7]*myId+b1.w;

  if constexpr (LAYER==1 || LAYER==2){
    if (lane < 16){
      float4 r0 = make_float4(fmaxf(o[0],0.f), fmaxf(o[1],0.f), fmaxf(o[2],0.f), fmaxf(o[3],0.f));
      float4 r1 = make_float4(fmaxf(o[4],0.f), fmaxf(o[5],0.f), fmaxf(o[6],0.f), fmaxf(o[7],0.f));
      *(float4*)&hbuf[(long)wid*C + cg*8]     = r0;
      *(float4*)&hbuf[(long)wid*C + cg*8 + 4] = r1;
    }
    // head0 + head1 per feature d: lane l (cg<8) pairs with l+8
    float f[8];
    #pragma unroll
    for (int i=0;i<8;++i) f[i] = o[i] + __shfl_xor(o[i], 8, 64);
    if (lane < 8){
      float4 f0 = make_float4(f[0],f[1],f[2],f[3]);
      float4 f1 = make_float4(f[4],f[5],f[6],f[7]);
      float4* fp = (float4*)&fin[(long)wid*64 + lane*8];
      if constexpr (LAYER==1){
        const float4* src; long off;
        if      (wid < I_N)      { src=(const float4*)embi; off=(long)wid*16; }
        else if (wid < I_N+U_N)  { src=(const float4*)embu; off=(long)(wid-I_N)*16; }
        else                     { src=(const float4*)embf; off=(long)(wid-I_N-U_N)*16; }
        float4 xa = src[off + lane*2], xb = src[off + lane*2 + 1];
        fp[0] = make_float4(xa.x+f0.x*0.5f, xa.y+f0.y*0.5f, xa.z+f0.z*0.5f, xa.w+f0.w*0.5f);
        fp[1] = make_float4(xb.x+f1.x*0.5f, xb.y+f1.y*0.5f, xb.z+f1.z*0.5f, xb.w+f1.w*0.5f);
      } else {
        float4 ca = fp[0], cb = fp[1];
        fp[0] = make_float4(ca.x+f0.x*0.5f, ca.y+f0.y*0.5f, ca.z+f0.z*0.5f, ca.w+f0.w*0.5f);
        fp[1] = make_float4(cb.x+f1.x*0.5f, cb.y+f1.y*0.5f, cb.z+f1.z*0.5f, cb.w+f1.w*0.5f);
      }
    }
  } else {
    // LAYER 3: final = (fin + x3)/4 -> both output copies
    if (lane < 8){
      const float4* fp = (const float4*)&fin[(long)wid*64 + lane*8];
      float4 ca = fp[0], cb = fp[1];
      float4 t0 = make_float4((ca.x+o[0])*0.25f,(ca.y+o[1])*0.25f,(ca.z+o[2])*0.25f,(ca.w+o[3])*0.25f);
      float4 t1 = make_float4((cb.x+o[4])*0.25f,(cb.y+o[5])*0.25f,(cb.z+o[6])*0.25f,(cb.w+o[7])*0.25f);
      ((float4*)outp)[(long)wid*16 + lane*2]            = t0;
      ((float4*)outp)[(long)wid*16 + lane*2 + 1]        = t1;
      ((float4*)outp)[(long)(NN+wid)*16 + lane*2]       = t0;
      ((float4*)outp)[(long)(NN+wid)*16 + lane*2 + 1]   = t1;
    }
  }

  // fused alpha output
  if (segLen <= 64){
    if (lane < segLen){
      if constexpr (H==2)
        ((float2*)aout)[eid] = make_float2(p[0]*idv[0], p[1]*idv[1]);
      else
        aout[eid] = p[0]*idv[0];
    }
  } else {
    for (int base = n0; base < n1; base += 64){
      int cnt = n1 - base; if (cnt > 64) cnt = 64;
      if (lane < cnt){
        int ss = colsrc[base + lane];
        int ee = eids[base + lane];
        if constexpr (H==2){
          float2 a = ((const float2*)asrc)[ss];
          float w0 = __expf(leaky(a.x + ad[0]) - mx[0]) * idv[0];
          float w1 = __expf(leaky(a.y + ad[1]) - mx[1]) * idv[1];
          ((float2*)aout)[ee] = make_float2(w0, w1);
        } else {
          aout[ee] = __expf(leaky(asrc[ss] + ad[0]) - mx[0]) * idv[0];
        }
      }
    }
  }
}

extern "C" void kernel_launch(void* const* d_in, const int* in_sizes, int n_in,
                              void* d_out, int out_size, void* d_ws, size_t ws_size,
                              hipStream_t stream)
{
  (void)in_sizes; (void)n_in; (void)out_size; (void)ws_size;
  const int*   eidx  = (const int*)d_in[0];
  const int*   esrc  = eidx;
  const int*   edst  = eidx + EE;
  const float* emb_i = (const float*)d_in[1];
  const float* emb_u = (const float*)d_in[2];
  const float* emb_f = (const float*)d_in[3];
  const float* W1    = (const float*)d_in[4];
  const float* as1   = (const float*)d_in[5];
  const float* ad1   = (const float*)d_in[6];
  const float* b1    = (const float*)d_in[7];
  const float* W2    = (const float*)d_in[8];
  const float* as2   = (const float*)d_in[9];
  const float* ad2   = (const float*)d_in[10];
  const float* b2    = (const float*)d_in[11];
  const float* W3    = (const float*)d_in[12];
  const float* as3   = (const float*)d_in[13];
  const float* ad3   = (const float*)d_in[14];
  const float* b3    = (const float*)d_in[15];
  float* out = (float*)d_out;

  // workspace layout (256B aligned)
  char* p = (char*)d_ws;
  auto alloc = [&](size_t bytes)->char* {
    char* r = p; p += (bytes + 255) & ~(size_t)255; return r;
  };
  float*  fin  = (float*)alloc((size_t)NN*64*4);
  float*  hbuf = (float*)alloc((size_t)NN*128*4);
  __half* xwh  = (__half*)alloc((size_t)NN*128*2);
  float*  asrc = (float*)alloc((size_t)NN*2*4);
  float*  adst = (float*)alloc((size_t)NN*2*4);
  int* row_start = (int*)alloc((size_t)(NN+1)*4);
  int* colsrc    = (int*)alloc((size_t)ETOT*4);
  int* eids      = (int*)alloc((size_t)ETOT*4);
  unsigned long long* binned = (unsigned long long*)alloc((size_t)EE*8);
  int* bsize     = (int*)alloc((size_t)NBUCK*4);
  int* ebase     = (int*)alloc((size_t)NBUCK*4);
  int* rbase     = (int*)alloc((size_t)NBUCK*4);
  int* gcur      = (int*)alloc((size_t)NBUCK*4);

  float* alpha1 = out + (size_t)12800000;
  float* alpha2 = out + (size_t)15400000;
  float* alpha3 = out + (size_t)18000000;

  // binned CSR build (shared by all layers)
  constexpr int NB_CHUNK = (EE + 4095)/4096;   // 293
  zerob_k   <<<1, 256, 0, stream>>>(bsize);
  hist_k    <<<512, 256, 0, stream>>>(edst, bsize);
  bscan_k   <<<1, 256, 0, stream>>>(bsize, ebase, rbase, gcur, row_start);
  binplace_k<<<NB_CHUNK, 256, 0, stream>>>(esrc, edst, gcur, binned);
  bbuild_k  <<<NBUCK, 512, 0, stream>>>(binned, bsize, ebase, rbase, row_start, colsrc, eids);

  // ---- Layer 1: K=64 -> C=128 (H=2), X = concat(embeddings) ----
  gemm_att_k<64,128,64,32,true><<<NN/32,256,0,stream>>>(emb_i, emb_u, emb_f, W1, as1, ad1, xwh, asrc, adst);
  aggregate_k<2,1><<<NN/4,256,0,stream>>>(xwh, asrc, adst, row_start, colsrc, eids, b1, alpha1,
                                          hbuf, fin, emb_i, emb_u, emb_f, nullptr);

  // ---- Layer 2: K=128 -> C=128 (H=2) ----
  gemm_att_k<128,128,64,32,false><<<NN/32,256,0,stream>>>(hbuf, nullptr, nullptr, W2, as2, ad2, xwh, asrc, adst);
  aggregate_k<2,2><<<NN/4,256,0,stream>>>(xwh, asrc, adst, row_start, colsrc, eids, b2, alpha2,
                                          hbuf, fin, nullptr, nullptr, nullptr, nullptr);

  // ---- Layer 3: K=128 -> C=64 (H=1), fused final write ----
  gemm_att_k<128,64,128,32,false><<<NN/32,256,0,stream>>>(hbuf, nullptr, nullptr, W3, as3, ad3, xwh, asrc, adst);
  aggregate_k<1,3><<<NN/4,256,0,stream>>>(xwh, asrc, adst, row_start, colsrc, eids, b3, alpha3,
                                          nullptr, fin, nullptr, nullptr, nullptr, out);
}

// Round 7
// 478.770 us; speedup vs baseline: 1.3310x; 1.1018x over previous
//
#include <hip/hip_runtime.h>
#include <hip/hip_fp16.h>
#include <math.h>

// Problem constants (fixed by reference)
constexpr int I_N = 40000, U_N = 30000, F_N = 30000;
constexpr int NN   = 100000;           // total nodes
constexpr int EE   = 1200000;          // edges (without self loops)
constexpr int ETOT = EE + NN;          // edges + self loops
constexpr int NBUCK = (NN + 511)/512;  // 196 dst-buckets of 512 nodes

using half8  = __attribute__((ext_vector_type(8))) _Float16;
using floatx4 = __attribute__((ext_vector_type(4))) float;

__device__ __forceinline__ float leaky(float x){ return x > 0.f ? x : 0.2f*x; }

// ---------------- binned CSR build (no random global atomics in hot path) ----------------
__global__ __launch_bounds__(256) void zerob_k(int* bsize){
  int i = threadIdx.x;
  if (i < NBUCK) bsize[i] = 0;
}

__global__ __launch_bounds__(256) void hist_k(const int* __restrict__ edst, int* __restrict__ bsize){
  __shared__ int h[NBUCK];
  for (int i = threadIdx.x; i < NBUCK; i += 256) h[i] = 0;
  __syncthreads();
  int stride = gridDim.x*256;
  for (int e = blockIdx.x*256 + threadIdx.x; e < EE; e += stride)
    atomicAdd(&h[edst[e] >> 9], 1);
  __syncthreads();
  for (int i = threadIdx.x; i < NBUCK; i += 256)
    if (h[i]) atomicAdd(&bsize[i], h[i]);
}

__global__ __launch_bounds__(256) void bscan_k(const int* __restrict__ bsize,
                                               int* __restrict__ ebase, int* __restrict__ rbase,
                                               int* __restrict__ gcur, int* __restrict__ row_start){
  __shared__ int sb[NBUCK], se[NBUCK], sr[NBUCK];
  int t = threadIdx.x;
  for (int i = t; i < NBUCK; i += 256) sb[i] = bsize[i];
  __syncthreads();
  if (t == 0){
    int e = 0, r = 0;
    for (int b = 0; b < NBUCK; ++b){
      int nloc = NN - b*512; if (nloc > 512) nloc = 512;
      se[b] = e; sr[b] = r;
      e += sb[b]; r += sb[b] + nloc;
    }
    row_start[NN] = ETOT;
  }
  __syncthreads();
  for (int i = t; i < NBUCK; i += 256){
    ebase[i] = se[i]; gcur[i] = se[i]; rbase[i] = sr[i];
  }
}

__global__ __launch_bounds__(256) void binplace_k(const int* __restrict__ esrc,
                                                  const int* __restrict__ edst,
                                                  int* __restrict__ gcur,
                                                  unsigned long long* __restrict__ binned){
  constexpr int CHUNK = 4096;
  __shared__ int ls[CHUNK], ld[CHUNK];
  __shared__ int h[NBUCK], bb[NBUCK], cur[NBUCK];
  long e0 = (long)blockIdx.x * CHUNK;
  int n = (int)(EE - e0); if (n > CHUNK) n = CHUNK;
  for (int i = threadIdx.x; i < NBUCK; i += 256){ h[i] = 0; cur[i] = 0; }
  __syncthreads();
  for (int i = threadIdx.x; i < n; i += 256){
    int s = esrc[e0+i], d = edst[e0+i];
    ls[i] = s; ld[i] = d;
    atomicAdd(&h[d >> 9], 1);
  }
  __syncthreads();
  for (int b = threadIdx.x; b < NBUCK; b += 256)
    bb[b] = h[b] ? atomicAdd(&gcur[b], h[b]) : 0;
  __syncthreads();
  for (int i = threadIdx.x; i < n; i += 256){
    int d = ld[i], b = d >> 9;
    int p = bb[b] + atomicAdd(&cur[b], 1);
    unsigned long long v = ((unsigned long long)(unsigned)(e0+i) << 32)
                         | (unsigned)(ls[i] | ((d & 511) << 17));
    binned[p] = v;
  }
}

__global__ __launch_bounds__(512) void bbuild_k(const unsigned long long* __restrict__ binned,
                                                const int* __restrict__ bsize,
                                                const int* __restrict__ ebase, const int* __restrict__ rbase,
                                                int* __restrict__ row_start,
                                                int* __restrict__ colsrc, int* __restrict__ eids){
  __shared__ int sm[512], curs[512];
  int b = blockIdx.x, t = threadIdx.x;
  int nbase = b*512;
  int NLOC = NN - nbase; if (NLOC > 512) NLOC = 512;
  int sz = bsize[b], eb = ebase[b], rb = rbase[b];
  sm[t] = (t < NLOC) ? 1 : 0;                  // self loop
  __syncthreads();
  for (int i = t; i < sz; i += 512){
    int lo = (int)(binned[eb+i] & 0xFFFFFFFFu);
    atomicAdd(&sm[(lo >> 17) & 511], 1);
  }
  __syncthreads();
  int myc = sm[t];
  for (int off = 1; off < 512; off <<= 1){
    int x = (t >= off) ? sm[t-off] : 0;
    __syncthreads();
    sm[t] += x;
    __syncthreads();
  }
  int excl = sm[t] - myc;
  if (t < NLOC){
    row_start[nbase+t] = rb + excl;
    colsrc[rb+excl] = nbase + t;               // self loop first in segment
    eids[rb+excl]   = EE + nbase + t;
  }
  curs[t] = excl + ((t < NLOC) ? 1 : 0);
  __syncthreads();
  for (int i = t; i < sz; i += 512){
    unsigned long long v = binned[eb+i];
    int lo  = (int)(v & 0xFFFFFFFFu);
    int dl  = (lo >> 17) & 511;
    int src = lo & 0x1FFFF;
    int p = rb + atomicAdd(&curs[dl], 1);
    colsrc[p] = src;
    eids[p]   = (int)(v >> 32);
  }
}

// ---------------- one-time weight transpose W(KxC) -> WT(CxK) fp16 ----------------
__global__ __launch_bounds__(256) void wtrans_k(const float* __restrict__ W1,
                                                const float* __restrict__ W2,
                                                const float* __restrict__ W3,
                                                __half* __restrict__ wt1,
                                                __half* __restrict__ wt2,
                                                __half* __restrict__ wt3){
  int i = blockIdx.x*256 + threadIdx.x;
  if (i < 64*128){  int k = i >> 7, c = i & 127; wt1[c*64  + k] = __float2half(W1[i]); }
  if (i < 128*128){ int k = i >> 7, c = i & 127; wt2[c*128 + k] = __float2half(W2[i]); }
  if (i < 128*64){  int k = i >> 6, c = i & 63;  wt3[c*128 + k] = __float2half(W3[i]); }
}

// ---------------- MFMA GEMM (+ fused attention dots) ----------------
// XWH(fp16) = X @ W via v_mfma_f32_16x16x32_f16; WT is pre-transposed fp16 [C][K].
// Block: 256 thr = 4 waves, RPB=64 rows; wave w handles rows [w*16,w*16+16), all C cols.
// A-frag: lane holds X[row=l&15][k=ks*32+(l>>4)*8 + j] (contiguous, b128 read).
// B-frag: lane holds W[k][col=l&15] = WT[col][k]     (contiguous, b128 read).
// C/D: col=lane&15, row=(lane>>4)*4+reg.
template<int K, int C, bool CONCAT>
__global__ __launch_bounds__(256) void gemm_mfma_k(
    const float* __restrict__ Xa, const float* __restrict__ Xb, const float* __restrict__ Xc,
    const __half* __restrict__ WT,
    const float* __restrict__ atts, const float* __restrict__ attd,
    __half* __restrict__ XWH, float* __restrict__ asrc, float* __restrict__ adst)
{
  constexpr int RPB = 64;
  constexpr int H   = C/64;
  constexpr int NCT = C/16;
  constexpr size_t STAGE_B = (size_t)(RPB*K + C*K)*2;
  constexpr size_t EPI_B   = (size_t)RPB*(C+4)*4;
  constexpr size_t SMEM_B  = STAGE_B > EPI_B ? STAGE_B : EPI_B;
  __shared__ __align__(16) char smem[SMEM_B];
  _Float16* Xs = (_Float16*)smem;          // [RPB][K]
  _Float16* Bs = Xs + RPB*K;               // [C][K]
  float*    Es = (float*)smem;             // [RPB][C+4] epilogue

  int t = threadIdx.x;
  long rbase = (long)blockIdx.x * RPB;

  // stage X tile (fp32 -> fp16)
  for (int i = t; i < RPB*K/4; i += 256){
    float4 v = make_float4(0.f,0.f,0.f,0.f);
    if constexpr (CONCAT){
      long gi = rbase*(K/4) + i;
      if      (gi < (long)I_N*(K/4))        v = ((const float4*)Xa)[gi];
      else if (gi < (long)(I_N+U_N)*(K/4))  v = ((const float4*)Xb)[gi - (long)I_N*(K/4)];
      else if (gi < (long)NN*(K/4))         v = ((const float4*)Xc)[gi - (long)(I_N+U_N)*(K/4)];
    } else {
      if (rbase + i/(K/4) < NN)             v = ((const float4*)(Xa + rbase*K))[i];
    }
    union { __half2 h2[2]; uint2 u; } pk;
    pk.h2[0] = __floats2half2_rn(v.x, v.y);
    pk.h2[1] = __floats2half2_rn(v.z, v.w);
    ((uint2*)Xs)[i] = pk.u;
  }
  // stage WT tile (fp16 copy)
  for (int i = t; i < C*K/8; i += 256)
    ((uint4*)Bs)[i] = ((const uint4*)WT)[i];
  __syncthreads();

  const int wid = t >> 6, lane = t & 63;
  const int l15 = lane & 15, lk = lane >> 4;
  floatx4 acc[NCT];
  #pragma unroll
  for (int i = 0; i < NCT; ++i) acc[i] = (floatx4){0.f,0.f,0.f,0.f};

  const _Float16* arow = Xs + (wid*16 + l15)*K + lk*8;
  const _Float16* brow = Bs + l15*K + lk*8;
  #pragma unroll
  for (int ks = 0; ks < K/32; ++ks){
    half8 a = *(const half8*)(arow + ks*32);
    #pragma unroll
    for (int ct = 0; ct < NCT; ++ct){
      half8 b = *(const half8*)(brow + ct*16*K + ks*32);
      acc[ct] = __builtin_amdgcn_mfma_f32_16x16x32_f16(a, b, acc[ct], 0, 0, 0);
    }
  }

  // attention dot products from fp32 accumulators
  float asv[NCT], adv[NCT];
  #pragma unroll
  for (int ct = 0; ct < NCT; ++ct){
    asv[ct] = atts[ct*16 + l15];
    adv[ct] = attd[ct*16 + l15];
  }
  #pragma unroll
  for (int reg = 0; reg < 4; ++reg){
    float p0s = 0.f, p0d = 0.f, p1s = 0.f, p1d = 0.f;
    #pragma unroll
    for (int ct = 0; ct < NCT; ++ct){
      float v = acc[ct][reg];
      if (H == 2 && ct >= NCT/2){ p1s = fmaf(v, asv[ct], p1s); p1d = fmaf(v, adv[ct], p1d); }
      else                      { p0s = fmaf(v, asv[ct], p0s); p0d = fmaf(v, adv[ct], p0d); }
    }
    #pragma unroll
    for (int m = 1; m < 16; m <<= 1){
      p0s += __shfl_xor(p0s, m, 64); p0d += __shfl_xor(p0d, m, 64);
      if (H == 2){ p1s += __shfl_xor(p1s, m, 64); p1d += __shfl_xor(p1d, m, 64); }
    }
    if (l15 == 0){
      long r = rbase + wid*16 + lk*4 + reg;
      if (r < NN){
        asrc[r*H] = p0s; adst[r*H] = p0d;
        if (H == 2){ asrc[r*H+1] = p1s; adst[r*H+1] = p1d; }
      }
    }
  }

  // epilogue: acc -> LDS (fp32, padded) -> coalesced fp16 global store
  __syncthreads();
  #pragma unroll
  for (int ct = 0; ct < NCT; ++ct)
    #pragma unroll
    for (int reg = 0; reg < 4; ++reg)
      Es[(wid*16 + lk*4 + reg)*(C+4) + ct*16 + l15] = acc[ct][reg];
  __syncthreads();
  for (int i = t; i < RPB*C/4; i += 256){
    int row = i/(C/4), c4 = (i%(C/4))*4;
    if (rbase + row >= NN) continue;
    float4 v = *(const float4*)&Es[row*(C+4) + c4];
    union { __half2 h2[2]; uint2 u; } pk;
    pk.h2[0] = __floats2half2_rn(v.x, v.y);
    pk.h2[1] = __floats2half2_rn(v.z, v.w);
    *(uint2*)&XWH[(rbase+row)*C + c4] = pk.u;
  }
}

// ---------------- aggregation: online softmax + weighted sum + fused alpha/final ------
// (verbatim from round 6 — passing at ~92 us)
template<int H, int LAYER>
__global__ __launch_bounds__(256) void aggregate_k(
    const __half* __restrict__ XWH, const float* __restrict__ asrc, const float* __restrict__ adst,
    const int* __restrict__ row_start, const int* __restrict__ colsrc, const int* __restrict__ eids,
    const float* __restrict__ bias, float* __restrict__ aout,
    float* __restrict__ hbuf, float* __restrict__ fin,
    const float* __restrict__ embi, const float* __restrict__ embu, const float* __restrict__ embf,
    float* __restrict__ outp)
{
  constexpr int C = H*64;
  int wid  = (blockIdx.x*256 + threadIdx.x) >> 6;
  int lane = threadIdx.x & 63;
  if (wid >= NN) return;
  int n0 = row_start[wid], n1 = row_start[wid+1];
  int segLen = n1 - n0;

  float ad[H];
  if constexpr (H==2){ float2 t = ((const float2*)adst)[wid]; ad[0]=t.x; ad[1]=t.y; }
  else                 ad[0] = adst[wid];

  constexpr int SL_SH = (H==2) ? 4 : 3;
  const int slot = lane >> SL_SH;
  const int cg   = lane & ((1<<SL_SH)-1);
  const int hd   = (H==2) ? (cg>>3) : 0;

  float mx[H], den[H];
  #pragma unroll
  for (int h=0; h<H; ++h){ mx[h] = -3.402823466e38f; den[h] = 0.f; }
  float accv[8];
  #pragma unroll
  for (int i=0;i<8;++i) accv[i] = 0.f;

  int s = 0, eid = 0;
  float p[H];
  #pragma unroll
  for (int h=0; h<H; ++h) p[h] = 0.f;

  for (int base = n0; base < n1; base += 64){
    int cnt = n1 - base; if (cnt > 64) cnt = 64;
    float e[H];
    #pragma unroll
    for (int h=0; h<H; ++h) e[h] = -3.402823466e38f;
    if (lane < cnt){
      s   = colsrc[base + lane];
      eid = eids[base + lane];
      if constexpr (H==2){
        float2 a = ((const float2*)asrc)[s];
        e[0] = leaky(a.x + ad[0]); e[1] = leaky(a.y + ad[1]);
      } else {
        e[0] = leaky(asrc[s] + ad[0]);
      }
    }
    float sc[H];
    #pragma unroll
    for (int h=0; h<H; ++h){
      float bm = e[h];
      #pragma unroll
      for (int m=1; m<64; m<<=1) bm = fmaxf(bm, __shfl_xor(bm, m, 64));
      float nm = fmaxf(mx[h], bm);
      p[h] = (lane < cnt) ? __expf(e[h] - nm) : 0.f;
      if (base == n0){
        den[h] = p[h]; sc[h] = 1.f;
      } else {
        sc[h] = __expf(mx[h] - nm);
        den[h] = den[h]*sc[h] + p[h];
      }
      mx[h] = nm;
    }
    if (base != n0){
      float asc = (H==2) ? sc[hd] : sc[0];
      #pragma unroll
      for (int i=0;i<8;++i) accv[i] *= asc;
    }

    constexpr int EPI = 64 >> SL_SH;
    for (int j = 0; j < cnt; j += 2*EPI){
      float4 raw[2]; float q[2];
      #pragma unroll
      for (int u=0; u<2; ++u){
        int ei  = j + u*EPI + slot;
        int eic = ei < cnt ? ei : 0;
        int su  = __shfl(s, eic, 64);
        if constexpr (H==2){
          float q0 = __shfl(p[0], eic, 64);
          float q1 = __shfl(p[1], eic, 64);
          q[u] = (ei < cnt) ? (hd ? q1 : q0) : 0.f;
        } else {
          float q0 = __shfl(p[0], eic, 64);
          q[u] = (ei < cnt) ? q0 : 0.f;
        }
        raw[u] = *(const float4*)&XWH[(long)su*C + cg*8];
      }
      #pragma unroll
      for (int u=0; u<2; ++u){
        union { float4 f4; __half2 h2[4]; } cv; cv.f4 = raw[u];
        #pragma unroll
        for (int i=0;i<4;++i){
          float2 f = __half22float2(cv.h2[i]);
          accv[2*i]   = fmaf(q[u], f.x, accv[2*i]);
          accv[2*i+1] = fmaf(q[u], f.y, accv[2*i+1]);
        }
      }
    }
  }

  float idv[H];
  #pragma unroll
  for (int h=0; h<H; ++h){
    #pragma unroll
    for (int m=1; m<64; m<<=1) den[h] += __shfl_xor(den[h], m, 64);
    idv[h] = 1.0f/(den[h] + 1e-16f);
  }

  #pragma unroll
  for (int i=0;i<8;++i){
    if constexpr (H==1) accv[i] += __shfl_xor(accv[i], 8, 64);
    accv[i] += __shfl_xor(accv[i], 16, 64);
    accv[i] += __shfl_xor(accv[i], 32, 64);
  }

  float myId = (H==2) ? idv[hd] : idv[0];
  float4 b0 = *(const float4*)&bias[cg*8];
  float4 b1 = *(const float4*)&bias[cg*8 + 4];
  float o[8];
  o[0]=accv[0]*myId+b0.x; o[1]=accv[1]*myId+b0.y; o[2]=accv[2]*myId+b0.z; o[3]=accv[3]*myId+b0.w;
  o[4]=accv[4]*myId+b1.x; o[5]=accv[5]*myId+b1.y; o[6]=accv[6]*myId+b1.z; o[7]=accv[7]*myId+b1.w;

  if constexpr (LAYER==1 || LAYER==2){
    if (lane < 16){
      float4 r0 = make_float4(fmaxf(o[0],0.f), fmaxf(o[1],0.f), fmaxf(o[2],0.f), fmaxf(o[3],0.f));
      float4 r1 = make_float4(fmaxf(o[4],0.f), fmaxf(o[5],0.f), fmaxf(o[6],0.f), fmaxf(o[7],0.f));
      *(float4*)&hbuf[(long)wid*C + cg*8]     = r0;
      *(float4*)&hbuf[(long)wid*C + cg*8 + 4] = r1;
    }
    float f[8];
    #pragma unroll
    for (int i=0;i<8;++i) f[i] = o[i] + __shfl_xor(o[i], 8, 64);
    if (lane < 8){
      float4 f0 = make_float4(f[0],f[1],f[2],f[3]);
      float4 f1 = make_float4(f[4],f[5],f[6],f[7]);
      float4* fp = (float4*)&fin[(long)wid*64 + lane*8];
      if constexpr (LAYER==1){
        const float4* src; long off;
        if      (wid < I_N)      { src=(const float4*)embi; off=(long)wid*16; }
        else if (wid < I_N+U_N)  { src=(const float4*)embu; off=(long)(wid-I_N)*16; }
        else                     { src=(const float4*)embf; off=(long)(wid-I_N-U_N)*16; }
        float4 xa = src[off + lane*2], xb = src[off + lane*2 + 1];
        fp[0] = make_float4(xa.x+f0.x*0.5f, xa.y+f0.y*0.5f, xa.z+f0.z*0.5f, xa.w+f0.w*0.5f);
        fp[1] = make_float4(xb.x+f1.x*0.5f, xb.y+f1.y*0.5f, xb.z+f1.z*0.5f, xb.w+f1.w*0.5f);
      } else {
        float4 ca = fp[0], cb = fp[1];
        fp[0] = make_float4(ca.x+f0.x*0.5f, ca.y+f0.y*0.5f, ca.z+f0.z*0.5f, ca.w+f0.w*0.5f);
        fp[1] = make_float4(cb.x+f1.x*0.5f, cb.y+f1.y*0.5f, cb.z+f1.z*0.5f, cb.w+f1.w*0.5f);
      }
    }
  } else {
    if (lane < 8){
      const float4* fp = (const float4*)&fin[(long)wid*64 + lane*8];
      float4 ca = fp[0], cb = fp[1];
      float4 t0 = make_float4((ca.x+o[0])*0.25f,(ca.y+o[1])*0.25f,(ca.z+o[2])*0.25f,(ca.w+o[3])*0.25f);
      float4 t1 = make_float4((cb.x+o[4])*0.25f,(cb.y+o[5])*0.25f,(cb.z+o[6])*0.25f,(cb.w+o[7])*0.25f);
      ((float4*)outp)[(long)wid*16 + lane*2]            = t0;
      ((float4*)outp)[(long)wid*16 + lane*2 + 1]        = t1;
      ((float4*)outp)[(long)(NN+wid)*16 + lane*2]       = t0;
      ((float4*)outp)[(long)(NN+wid)*16 + lane*2 + 1]   = t1;
    }
  }

  if (segLen <= 64){
    if (lane < segLen){
      if constexpr (H==2)
        ((float2*)aout)[eid] = make_float2(p[0]*idv[0], p[1]*idv[1]);
      else
        aout[eid] = p[0]*idv[0];
    }
  } else {
    for (int base = n0; base < n1; base += 64){
      int cnt = n1 - base; if (cnt > 64) cnt = 64;
      if (lane < cnt){
        int ss = colsrc[base + lane];
        int ee = eids[base + lane];
        if constexpr (H==2){
          float2 a = ((const float2*)asrc)[ss];
          float w0 = __expf(leaky(a.x + ad[0]) - mx[0]) * idv[0];
          float w1 = __expf(leaky(a.y + ad[1]) - mx[1]) * idv[1];
          ((float2*)aout)[ee] = make_float2(w0, w1);
        } else {
          aout[ee] = __expf(leaky(asrc[ss] + ad[0]) - mx[0]) * idv[0];
        }
      }
    }
  }
}

extern "C" void kernel_launch(void* const* d_in, const int* in_sizes, int n_in,
                              void* d_out, int out_size, void* d_ws, size_t ws_size,
                              hipStream_t stream)
{
  (void)in_sizes; (void)n_in; (void)out_size; (void)ws_size;
  const int*   eidx  = (const int*)d_in[0];
  const int*   esrc  = eidx;
  const int*   edst  = eidx + EE;
  const float* emb_i = (const float*)d_in[1];
  const float* emb_u = (const float*)d_in[2];
  const float* emb_f = (const float*)d_in[3];
  const float* W1    = (const float*)d_in[4];
  const float* as1   = (const float*)d_in[5];
  const float* ad1   = (const float*)d_in[6];
  const float* b1    = (const float*)d_in[7];
  const float* W2    = (const float*)d_in[8];
  const float* as2   = (const float*)d_in[9];
  const float* ad2   = (const float*)d_in[10];
  const float* b2    = (const float*)d_in[11];
  const float* W3    = (const float*)d_in[12];
  const float* as3   = (const float*)d_in[13];
  const float* ad3   = (const float*)d_in[14];
  const float* b3    = (const float*)d_in[15];
  float* out = (float*)d_out;

  // workspace layout (256B aligned)
  char* p = (char*)d_ws;
  auto alloc = [&](size_t bytes)->char* {
    char* r = p; p += (bytes + 255) & ~(size_t)255; return r;
  };
  float*  fin  = (float*)alloc((size_t)NN*64*4);
  float*  hbuf = (float*)alloc((size_t)NN*128*4);
  __half* xwh  = (__half*)alloc((size_t)NN*128*2);
  float*  asrc = (float*)alloc((size_t)NN*2*4);
  float*  adst = (float*)alloc((size_t)NN*2*4);
  int* row_start = (int*)alloc((size_t)(NN+1)*4);
  int* colsrc    = (int*)alloc((size_t)ETOT*4);
  int* eids      = (int*)alloc((size_t)ETOT*4);
  unsigned long long* binned = (unsigned long long*)alloc((size_t)EE*8);
  int* bsize     = (int*)alloc((size_t)NBUCK*4);
  int* ebase     = (int*)alloc((size_t)NBUCK*4);
  int* rbase     = (int*)alloc((size_t)NBUCK*4);
  int* gcur      = (int*)alloc((size_t)NBUCK*4);
  __half* wt1    = (__half*)alloc((size_t)128*64*2);
  __half* wt2    = (__half*)alloc((size_t)128*128*2);
  __half* wt3    = (__half*)alloc((size_t)64*128*2);

  float* alpha1 = out + (size_t)12800000;
  float* alpha2 = out + (size_t)15400000;
  float* alpha3 = out + (size_t)18000000;

  // binned CSR build + weight transpose
  constexpr int NB_CHUNK = (EE + 4095)/4096;   // 293
  constexpr int NB_GEMM  = (NN + 63)/64;       // 1563
  zerob_k   <<<1, 256, 0, stream>>>(bsize);
  hist_k    <<<512, 256, 0, stream>>>(edst, bsize);
  bscan_k   <<<1, 256, 0, stream>>>(bsize, ebase, rbase, gcur, row_start);
  binplace_k<<<NB_CHUNK, 256, 0, stream>>>(esrc, edst, gcur, binned);
  wtrans_k  <<<64, 256, 0, stream>>>(W1, W2, W3, wt1, wt2, wt3);
  bbuild_k  <<<NBUCK, 512, 0, stream>>>(binned, bsize, ebase, rbase, row_start, colsrc, eids);

  // ---- Layer 1: K=64 -> C=128 (H=2), X = concat(embeddings) ----
  gemm_mfma_k<64,128,true><<<NB_GEMM,256,0,stream>>>(emb_i, emb_u, emb_f, wt1, as1, ad1, xwh, asrc, adst);
  aggregate_k<2,1><<<NN/4,256,0,stream>>>(xwh, asrc, adst, row_start, colsrc, eids, b1, alpha1,
                                          hbuf, fin, emb_i, emb_u, emb_f, nullptr);

  // ---- Layer 2: K=128 -> C=128 (H=2) ----
  gemm_mfma_k<128,128,false><<<NB_GEMM,256,0,stream>>>(hbuf, nullptr, nullptr, wt2, as2, ad2, xwh, asrc, adst);
  aggregate_k<2,2><<<NN/4,256,0,stream>>>(xwh, asrc, adst, row_start, colsrc, eids, b2, alpha2,
                                          hbuf, fin, nullptr, nullptr, nullptr, nullptr);

  // ---- Layer 3: K=128 -> C=64 (H=1), fused final write ----
  gemm_mfma_k<128,64,false><<<NB_GEMM,256,0,stream>>>(hbuf, nullptr, nullptr, wt3, as3, ad3, xwh, asrc, adst);
  aggregate_k<1,3><<<NN/4,256,0,stream>>>(xwh, asrc, adst, row_start, colsrc, eids, b3, alpha3,
                                          nullptr, fin, nullptr, nullptr, nullptr, out);
}